// Round 1
// baseline (1287.295 us; speedup 1.0000x reference)
//
#include <hip/hip_runtime.h>

// ---------------------------------------------------------------------------
// SelfMultiHeadAttn: x[B,S,H] -> LN(x + OutProj(SDPA(RoPE(q), RoPE(k/|k|), v)))
// B=2 S=2048 H=1024 R=16 heads, K=64 head dim. All fp32 in/out.
// R0 baseline: f16-MFMA GEMMs (128x128 tile), fp32 vector flash attention.
// ---------------------------------------------------------------------------

#define B_   2
#define S_   2048
#define H_   1024
#define R_   16
#define KH   64
#define BS_  (B_*S_)     // 4096 rows
#define NQKV 3072        // R*K*3
#define LOG2E 1.44269504088896f

typedef float    floatx4 __attribute__((ext_vector_type(4)));
typedef _Float16 half8   __attribute__((ext_vector_type(8)));
typedef _Float16 half4   __attribute__((ext_vector_type(4)));

// ---------------- cast fp32 -> fp16 (vectorized, n % 1024 == 0) ------------
__global__ __launch_bounds__(256) void cast_f16_kernel(
    const float* __restrict__ in, _Float16* __restrict__ out, int n)
{
    int i = (blockIdx.x * 256 + threadIdx.x) * 4;
    if (i >= n) return;
    float4 v = *(const float4*)(in + i);
    half4 h;
    h.x = (_Float16)v.x; h.y = (_Float16)v.y; h.z = (_Float16)v.z; h.w = (_Float16)v.w;
    *(half4*)(out + i) = h;
}

// --------- transpose + cast: in[rows][cols] f32 -> out[cols][rows] f16 -----
// rows, cols multiples of 32. Block 256 = 32x8.
__global__ __launch_bounds__(256) void transpose_cast_f16(
    const float* __restrict__ in, _Float16* __restrict__ out, int rows, int cols)
{
    __shared__ float tile[32][33];
    int bx = blockIdx.x * 32;   // col base
    int by = blockIdx.y * 32;   // row base
    int tx = threadIdx.x & 31, ty = threadIdx.x >> 5;   // ty in 0..7
#pragma unroll
    for (int i = 0; i < 32; i += 8)
        tile[ty + i][tx] = in[(size_t)(by + ty + i) * cols + bx + tx];
    __syncthreads();
#pragma unroll
    for (int i = 0; i < 32; i += 8)
        out[(size_t)(bx + ty + i) * rows + by + tx] = (_Float16)tile[tx][ty + i];
}

// ------------------- f16 MFMA GEMM:  C = A @ Bt^T + bias (+resid) ----------
// A[M][Kd] f16, Bt[N][Kd] f16 (i.e. B pre-transposed), C[M][N] f32.
// M,N % 128 == 0, Kd % 32 == 0. Block 256 thr = 4 waves (2x2), each wave
// computes a 64x64 sub-tile as 4x4 grid of 16x16x32 MFMAs.
// Fragment layouts (verified on gfx950, cdna_hip_programming.md §3):
//   A: lane holds A[m=lane&15][k = 8*(lane>>4) + j]   (8 f16, 16B contiguous)
//   B: lane holds B[k = 8*(lane>>4) + j][n=lane&15]   (= Bt[n][k], contiguous)
//   D: reg r holds D[row = 4*(lane>>4) + r][col = lane&15]
__global__ __launch_bounds__(256) void gemm_f16_mfma(
    const _Float16* __restrict__ A, const _Float16* __restrict__ Bt,
    const float* __restrict__ bias, const float* __restrict__ resid,
    float* __restrict__ C, int M, int N, int Kd)
{
    __shared__ _Float16 Als[128][32];
    __shared__ _Float16 Bls[128][32];
    int tid  = threadIdx.x;
    int lane = tid & 63, w = tid >> 6;
    int wr = w >> 1, wc = w & 1;
    int fr = lane & 15, fq = lane >> 4;
    int m0 = blockIdx.y * 128, n0 = blockIdx.x * 128;

    floatx4 acc[4][4] = {};

    // staging: thread loads 32B of one row (2 x float4 = 16 f16)
    int sr = tid >> 1, sc = (tid & 1) * 16;
    const float4* ga = (const float4*)(A  + (size_t)(m0 + sr) * Kd + sc);
    const float4* gb = (const float4*)(Bt + (size_t)(n0 + sr) * Kd + sc);
    float4* la = (float4*)&Als[sr][sc];
    float4* lb = (float4*)&Bls[sr][sc];

    for (int k0 = 0; k0 < Kd; k0 += 32) {
        float4 a0 = ga[0], a1 = ga[1];
        float4 b0 = gb[0], b1 = gb[1];
        ga += 4; gb += 4;                    // +32 f16 = +64B
        __syncthreads();                     // prev iter's frag reads done
        la[0] = a0; la[1] = a1;
        lb[0] = b0; lb[1] = b1;
        __syncthreads();
        half8 af[4], bf[4];
#pragma unroll
        for (int i = 0; i < 4; ++i)
            af[i] = *(const half8*)&Als[wr * 64 + i * 16 + fr][fq * 8];
#pragma unroll
        for (int j = 0; j < 4; ++j)
            bf[j] = *(const half8*)&Bls[wc * 64 + j * 16 + fr][fq * 8];
#pragma unroll
        for (int i = 0; i < 4; ++i)
#pragma unroll
            for (int j = 0; j < 4; ++j)
                acc[i][j] = __builtin_amdgcn_mfma_f32_16x16x32_f16(
                    af[i], bf[j], acc[i][j], 0, 0, 0);
    }

#pragma unroll
    for (int i = 0; i < 4; ++i)
#pragma unroll
        for (int j = 0; j < 4; ++j)
#pragma unroll
            for (int r2 = 0; r2 < 4; ++r2) {
                int row = m0 + wr * 64 + i * 16 + fq * 4 + r2;
                int col = n0 + wc * 64 + j * 16 + fr;
                float v = acc[i][j][r2] + bias[col];
                if (resid) v += resid[(size_t)row * N + col];
                C[(size_t)row * N + col] = v;
            }
}

// ---------- k-normalize + RoPE for q,k; write head-major q~,k~ -------------
// qkv[bs][3072]: per head r: q at r*192+[0,64), k at +64, v at +128.
// pos[bs][64]: sin = [0,32), cos = [32,64).
// out layout: qt/kt [B*R(head)][S][64]. One wave per (bs, r), 4 per block.
__global__ __launch_bounds__(256) void rope_kernel(
    const float* __restrict__ qkv, const float* __restrict__ pos,
    float* __restrict__ qt, float* __restrict__ kt)
{
    int task = blockIdx.x * 4 + (threadIdx.x >> 6);   // bs*16 + r
    int lane = threadIdx.x & 63;
    int r = task & 15, bs = task >> 4;
    int b = bs >> 11, s = bs & 2047;

    const float* base = qkv + (size_t)bs * NQKV + r * 192;
    float qv = base[lane];
    float kv = base[64 + lane];

    // L2-normalize k over the 64 lanes
    float ss = kv * kv;
#pragma unroll
    for (int off = 32; off > 0; off >>= 1) ss += __shfl_xor(ss, off);
    kv *= rsqrtf(ss);

    int j = lane & 31;
    float sn = pos[(size_t)bs * 64 + j];
    float cs = pos[(size_t)bs * 64 + 32 + j];
    float qp = __shfl_xor(qv, 32);
    float kp = __shfl_xor(kv, 32);
    float qo, ko;
    if (lane < 32) { qo = qv * cs - qp * sn; ko = kv * cs - kp * sn; }
    else           { qo = qp * sn + qv * cs; ko = kp * sn + kv * cs; }

    size_t oidx = ((size_t)(b * 16 + r) * S_ + s) * 64 + lane;
    qt[oidx] = qo;
    kt[oidx] = ko;
}

// ------------------- fp32 flash attention (online softmax) -----------------
// grid (32 heads, 32 q-blocks), block 256 = 4 waves. Each lane owns one
// query (q0+lane) with its q-vector + o-accumulator in VGPRs; the 4 waves
// split the 2048 keys 512 each (tiles of 16) and merge via LDS at the end.
__global__ __launch_bounds__(256) void attn_kernel(
    const float* __restrict__ qt, const float* __restrict__ kt,
    const float* __restrict__ qkv, float* __restrict__ ctx)
{
    __shared__ float Kls[4][16 * 64];
    __shared__ float Vls[4][16 * 64];
    __shared__ float cm[4][64], cl[4][64];
    __shared__ float obuf[64 * 65];

    int head = blockIdx.x;           // b*16 + r
    int q0   = blockIdx.y * 64;
    int b = head >> 4, r = head & 15;
    int lane = threadIdx.x & 63, w = threadIdx.x >> 6;

    float q[64];
    const float4* qb4 = (const float4*)(qt + ((size_t)head * S_ + q0 + lane) * 64);
#pragma unroll
    for (int d = 0; d < 16; ++d) {
        float4 t = qb4[d];
        q[4*d] = t.x; q[4*d+1] = t.y; q[4*d+2] = t.z; q[4*d+3] = t.w;
    }

    float m = -1e30f, l = 0.f, o[64];
#pragma unroll
    for (int d = 0; d < 64; ++d) o[d] = 0.f;

    float* Kl = Kls[w];
    float* Vl = Vls[w];

    for (int t16 = 0; t16 < 32; ++t16) {
        int j0 = w * 512 + t16 * 16;
        // stage K tile: 16 keys x 64 d = 256 float4, 4 per lane (contiguous)
        {
            const float4* ks = (const float4*)(kt + ((size_t)head * S_ + j0) * 64);
            float4* kd = (float4*)Kl;
#pragma unroll
            for (int i = 0; i < 4; ++i) kd[lane + 64 * i] = ks[lane + 64 * i];
        }
        // stage V tile straight from qkv (v = cols r*192+128..192)
        {
            int jj = lane >> 2, c4 = lane & 3;
            const float4* vs = (const float4*)(qkv + (size_t)(b * S_ + j0 + jj) * NQKV
                                               + r * 192 + 128 + c4 * 16);
            float4* vd = (float4*)(Vl + jj * 64 + c4 * 16);
#pragma unroll
            for (int i = 0; i < 4; ++i) vd[i] = vs[i];
        }
        __syncthreads();

        float p[16];
        float mt = m;
#pragma unroll
        for (int jj = 0; jj < 16; ++jj) {
            const float4* kr = (const float4*)(Kl + jj * 64);
            float s0 = 0.f, s1 = 0.f, s2 = 0.f, s3 = 0.f;
#pragma unroll
            for (int d = 0; d < 16; ++d) {
                float4 kk = kr[d];                 // broadcast LDS read
                s0 += q[4*d]   * kk.x; s1 += q[4*d+1] * kk.y;
                s2 += q[4*d+2] * kk.z; s3 += q[4*d+3] * kk.w;
            }
            p[jj] = (s0 + s1) + (s2 + s3);
            mt = fmaxf(mt, p[jj]);
        }
        float corr = exp2f((m - mt) * LOG2E);
        m = mt;
        l *= corr;
#pragma unroll
        for (int d = 0; d < 64; ++d) o[d] *= corr;
#pragma unroll
        for (int jj = 0; jj < 16; ++jj) {
            float pj = exp2f((p[jj] - m) * LOG2E);
            l += pj;
            p[jj] = pj;
        }
#pragma unroll
        for (int jj = 0; jj < 16; ++jj) {
            float pj = p[jj];
            const float4* vr = (const float4*)(Vl + jj * 64);
#pragma unroll
            for (int d = 0; d < 16; ++d) {
                float4 vv = vr[d];                 // broadcast LDS read
                o[4*d]   += pj * vv.x; o[4*d+1] += pj * vv.y;
                o[4*d+2] += pj * vv.z; o[4*d+3] += pj * vv.w;
            }
        }
        __syncthreads();
    }

    // ---- merge the 4 key-split partials ----
    cm[w][lane] = m; cl[w][lane] = l;
    __syncthreads();
    float M = fmaxf(fmaxf(cm[0][lane], cm[1][lane]), fmaxf(cm[2][lane], cm[3][lane]));
    float lsum = 0.f;
#pragma unroll
    for (int wi = 0; wi < 4; ++wi)
        lsum += cl[wi][lane] * exp2f((cm[wi][lane] - M) * LOG2E);
    float wscale = exp2f((m - M) * LOG2E);
    __syncthreads();                      // all cm/cl reads done before reuse
    if (w == 0) {
        cl[0][lane] = lsum;
#pragma unroll
        for (int d = 0; d < 64; ++d) obuf[d * 65 + lane] = o[d] * wscale;
    }
    __syncthreads();
    for (int wi = 1; wi < 4; ++wi) {
        if (w == wi) {
#pragma unroll
            for (int d = 0; d < 64; ++d) obuf[d * 65 + lane] += o[d] * wscale;
        }
        __syncthreads();
    }
    // store: wave w writes queries w*16..w*16+15, lane = d (coalesced)
    for (int t = 0; t < 16; ++t) {
        int qi = w * 16 + t;
        float val = obuf[lane * 65 + qi] / cl[0][qi];
        ctx[(size_t)(b * S_ + q0 + qi) * 1024 + r * 64 + lane] = val;
    }
}

// --------------------- LayerNorm in place on y[4096][1024] -----------------
__global__ __launch_bounds__(256) void ln_kernel(
    float* __restrict__ y, const float* __restrict__ g, const float* __restrict__ bb)
{
    int row = blockIdx.x, tid = threadIdx.x;
    float* p = y + (size_t)row * 1024;
    float4 v = ((const float4*)p)[tid];
    float sum = v.x + v.y + v.z + v.w;
    float sq  = v.x*v.x + v.y*v.y + v.z*v.z + v.w*v.w;
#pragma unroll
    for (int off = 32; off > 0; off >>= 1) {
        sum += __shfl_xor(sum, off);
        sq  += __shfl_xor(sq,  off);
    }
    __shared__ float rs[4], rq[4];
    int w = tid >> 6;
    if ((tid & 63) == 0) { rs[w] = sum; rq[w] = sq; }
    __syncthreads();
    sum = rs[0] + rs[1] + rs[2] + rs[3];
    sq  = rq[0] + rq[1] + rq[2] + rq[3];
    float mean = sum * (1.f / 1024.f);
    float var  = sq * (1.f / 1024.f) - mean * mean;
    float inv  = rsqrtf(var + 1e-5f);
    float4 gv = ((const float4*)g)[tid];
    float4 bv = ((const float4*)bb)[tid];
    v.x = (v.x - mean) * inv * gv.x + bv.x;
    v.y = (v.y - mean) * inv * gv.y + bv.y;
    v.z = (v.z - mean) * inv * gv.z + bv.z;
    v.w = (v.w - mean) * inv * gv.w + bv.w;
    ((float4*)p)[tid] = v;
}

// ---------------------------------------------------------------------------
extern "C" void kernel_launch(void* const* d_in, const int* in_sizes, int n_in,
                              void* d_out, int out_size, void* d_ws, size_t ws_size,
                              hipStream_t stream)
{
    const float* x     = (const float*)d_in[0];
    const float* pos   = (const float*)d_in[1];
    const float* W_qkv = (const float*)d_in[2];
    const float* b_qkv = (const float*)d_in[3];
    const float* W_out = (const float*)d_in[4];
    const float* b_out = (const float*)d_in[5];
    const float* ln_g  = (const float*)d_in[6];
    const float* ln_b  = (const float*)d_in[7];
    float* out = (float*)d_out;

    // workspace layout (120 MB total)
    char* ws = (char*)d_ws;
    _Float16* x_h    = (_Float16*)(ws);                       //  8 MB
    _Float16* wqkv_t = (_Float16*)(ws + ((size_t)8  << 20));  //  6 MB
    _Float16* wout_t = (_Float16*)(ws + ((size_t)14 << 20));  //  2 MB
    float*    qkv    = (float*)   (ws + ((size_t)16 << 20));  // 48 MB
    float*    qtb    = (float*)   (ws + ((size_t)64 << 20));  // 16 MB
    float*    ktb    = (float*)   (ws + ((size_t)80 << 20));  // 16 MB
    float*    ctxb   = (float*)   (ws + ((size_t)96 << 20));  // 16 MB
    _Float16* ctx_h  = (_Float16*)(ws + ((size_t)112 << 20)); //  8 MB

    // 1) casts / transposes
    cast_f16_kernel<<<4096, 256, 0, stream>>>(x, x_h, BS_ * H_);
    transpose_cast_f16<<<dim3(96, 32), 256, 0, stream>>>(W_qkv, wqkv_t, H_, NQKV);
    transpose_cast_f16<<<dim3(32, 32), 256, 0, stream>>>(W_out, wout_t, H_, H_);

    // 2) qkv = x @ W_qkv + b_qkv
    gemm_f16_mfma<<<dim3(NQKV / 128, BS_ / 128), 256, 0, stream>>>(
        x_h, wqkv_t, b_qkv, nullptr, qkv, BS_, NQKV, H_);

    // 3) k-normalize + RoPE -> head-major q~, k~
    rope_kernel<<<BS_ * R_ / 4, 256, 0, stream>>>(qkv, pos, qtb, ktb);

    // 4) SDPA -> ctx [BS][1024]
    attn_kernel<<<dim3(B_ * R_, S_ / 64), 256, 0, stream>>>(qtb, ktb, qkv, ctxb);

    // 5) out proj + bias + residual: y = x + ctx @ W_out + b_out  -> d_out
    cast_f16_kernel<<<4096, 256, 0, stream>>>(ctxb, ctx_h, BS_ * H_);
    gemm_f16_mfma<<<dim3(H_ / 128, BS_ / 128), 256, 0, stream>>>(
        ctx_h, wout_t, b_out, x, out, BS_, H_, H_);

    // 6) LayerNorm in place
    ln_kernel<<<BS_, 256, 0, stream>>>(out, ln_g, ln_b);
}

// Round 2
// 345.693 us; speedup vs baseline: 3.7238x; 3.7238x over previous
//
#include <hip/hip_runtime.h>

// ---------------------------------------------------------------------------
// SelfMultiHeadAttn: x[B,S,H] -> LN(x + OutProj(SDPA(RoPE(q), RoPE(k/|k|), v)))
// B=2 S=2048 H=1024 R=16 heads, K=64 head dim. fp32 in/out.
// R2: MFMA flash attention (16x16x32 f16, online softmax, LDS P-transform
//     with XOR bank swizzle), f16-MFMA GEMMs.
// ---------------------------------------------------------------------------

#define B_   2
#define S_   2048
#define H_   1024
#define R_   16
#define BS_  (B_*S_)     // 4096 rows
#define NQKV 3072        // R*K*3
#define LOG2E 1.44269504088896f

typedef float    floatx4 __attribute__((ext_vector_type(4)));
typedef _Float16 half8   __attribute__((ext_vector_type(8)));
typedef _Float16 half4   __attribute__((ext_vector_type(4)));

// ---------------- cast fp32 -> fp16 (vectorized, n % 1024 == 0) ------------
__global__ __launch_bounds__(256) void cast_f16_kernel(
    const float* __restrict__ in, _Float16* __restrict__ out, int n)
{
    int i = (blockIdx.x * 256 + threadIdx.x) * 4;
    if (i >= n) return;
    float4 v = *(const float4*)(in + i);
    half4 h;
    h.x = (_Float16)v.x; h.y = (_Float16)v.y; h.z = (_Float16)v.z; h.w = (_Float16)v.w;
    *(half4*)(out + i) = h;
}

// --------- transpose + cast: in[rows][cols] f32 -> out[cols][rows] f16 -----
__global__ __launch_bounds__(256) void transpose_cast_f16(
    const float* __restrict__ in, _Float16* __restrict__ out, int rows, int cols)
{
    __shared__ float tile[32][33];
    int bx = blockIdx.x * 32;   // col base
    int by = blockIdx.y * 32;   // row base
    int tx = threadIdx.x & 31, ty = threadIdx.x >> 5;   // ty in 0..7
#pragma unroll
    for (int i = 0; i < 32; i += 8)
        tile[ty + i][tx] = in[(size_t)(by + ty + i) * cols + bx + tx];
    __syncthreads();
#pragma unroll
    for (int i = 0; i < 32; i += 8)
        out[(size_t)(bx + ty + i) * rows + by + tx] = (_Float16)tile[tx][ty + i];
}

// ------------------- f16 MFMA GEMM:  C = A @ Bt^T + bias (+resid) ----------
// Fragment layouts verified in R1 (passed absmax 0.0156):
//   A: lane holds A[m=lane&15][k = 8*(lane>>4) + j]
//   B: lane holds B[k = 8*(lane>>4) + j][n=lane&15]   (reads Bt[n][k] contig)
//   D: reg r holds D[row = 4*(lane>>4) + r][col = lane&15]
__global__ __launch_bounds__(256) void gemm_f16_mfma(
    const _Float16* __restrict__ A, const _Float16* __restrict__ Bt,
    const float* __restrict__ bias, const float* __restrict__ resid,
    float* __restrict__ C, int M, int N, int Kd)
{
    __shared__ _Float16 Als[128][32];
    __shared__ _Float16 Bls[128][32];
    int tid  = threadIdx.x;
    int lane = tid & 63, w = tid >> 6;
    int wr = w >> 1, wc = w & 1;
    int fr = lane & 15, fq = lane >> 4;
    int m0 = blockIdx.y * 128, n0 = blockIdx.x * 128;

    floatx4 acc[4][4] = {};

    int sr = tid >> 1, sc = (tid & 1) * 16;
    const float4* ga = (const float4*)(A  + (size_t)(m0 + sr) * Kd + sc);
    const float4* gb = (const float4*)(Bt + (size_t)(n0 + sr) * Kd + sc);
    float4* la = (float4*)&Als[sr][sc];
    float4* lb = (float4*)&Bls[sr][sc];

    for (int k0 = 0; k0 < Kd; k0 += 32) {
        float4 a0 = ga[0], a1 = ga[1];
        float4 b0 = gb[0], b1 = gb[1];
        ga += 4; gb += 4;
        __syncthreads();
        la[0] = a0; la[1] = a1;
        lb[0] = b0; lb[1] = b1;
        __syncthreads();
        half8 af[4], bf[4];
#pragma unroll
        for (int i = 0; i < 4; ++i)
            af[i] = *(const half8*)&Als[wr * 64 + i * 16 + fr][fq * 8];
#pragma unroll
        for (int j = 0; j < 4; ++j)
            bf[j] = *(const half8*)&Bls[wc * 64 + j * 16 + fr][fq * 8];
#pragma unroll
        for (int i = 0; i < 4; ++i)
#pragma unroll
            for (int j = 0; j < 4; ++j)
                acc[i][j] = __builtin_amdgcn_mfma_f32_16x16x32_f16(
                    af[i], bf[j], acc[i][j], 0, 0, 0);
    }

#pragma unroll
    for (int i = 0; i < 4; ++i)
#pragma unroll
        for (int j = 0; j < 4; ++j)
#pragma unroll
            for (int r2 = 0; r2 < 4; ++r2) {
                int row = m0 + wr * 64 + i * 16 + fq * 4 + r2;
                int col = n0 + wc * 64 + j * 16 + fr;
                float v = acc[i][j][r2] + bias[col];
                if (resid) v += resid[(size_t)row * N + col];
                C[(size_t)row * N + col] = v;
            }
}

// ---------- k-normalize + RoPE for q,k; write head-major f16 q~,k~ ---------
// qkv[bs][3072]: per head r: q at r*192+[0,64), k at +64, v at +128.
// pos[bs][64]: sin = [0,32), cos = [32,64).
// qt/kt layout: [head=b*16+r][s][64] f16. One wave per (bs, r).
__global__ __launch_bounds__(256) void rope_kernel(
    const float* __restrict__ qkv, const float* __restrict__ pos,
    _Float16* __restrict__ qt, _Float16* __restrict__ kt)
{
    int task = blockIdx.x * 4 + (threadIdx.x >> 6);   // bs*16 + r
    int lane = threadIdx.x & 63;
    int r = task & 15, bs = task >> 4;
    int b = bs >> 11, s = bs & 2047;

    const float* base = qkv + (size_t)bs * NQKV + r * 192;
    float qv = base[lane];
    float kv = base[64 + lane];

    float ss = kv * kv;
#pragma unroll
    for (int off = 32; off > 0; off >>= 1) ss += __shfl_xor(ss, off);
    kv *= rsqrtf(ss);

    int j = lane & 31;
    float sn = pos[(size_t)bs * 64 + j];
    float cs = pos[(size_t)bs * 64 + 32 + j];
    float qp = __shfl_xor(qv, 32);
    float kp = __shfl_xor(kv, 32);
    float qo, ko;
    if (lane < 32) { qo = qv * cs - qp * sn; ko = kv * cs - kp * sn; }
    else           { qo = qp * sn + qv * cs; ko = kp * sn + kv * cs; }

    size_t oidx = ((size_t)(b * 16 + r) * S_ + s) * 64 + lane;
    qt[oidx] = (_Float16)qo;
    kt[oidx] = (_Float16)ko;
}

// ------- V transpose: qkv v-slice [bs][d] -> vt[head][d][s] f16 ------------
__global__ __launch_bounds__(256) void vtrans_kernel(
    const float* __restrict__ qkv, _Float16* __restrict__ vt)
{
    __shared__ float tile[64][65];
    int head = blockIdx.x, s0 = blockIdx.y * 64;
    int b = head >> 4, rh = head & 15;
    int tx = threadIdx.x & 63, ty = threadIdx.x >> 6;   // ty 0..3
#pragma unroll
    for (int si = ty; si < 64; si += 4)
        tile[si][tx] = qkv[(size_t)(b * S_ + s0 + si) * NQKV + rh * 192 + 128 + tx];
    __syncthreads();
#pragma unroll
    for (int d = ty; d < 64; d += 4)
        vt[((size_t)head * 64 + d) * S_ + s0 + tx] = (_Float16)tile[tx][d];
}

// ------------------- MFMA flash attention ----------------------------------
// grid (32 heads, 32 q-tiles), block 256 = 4 waves; wave w owns 16 queries.
// Per 64-key tile: S = Q@K^T (8 MFMAs), online softmax in C-layout,
// P C-layout -> A-layout via swizzled LDS round-trip, O += P@V (8 MFMAs).
__global__ __launch_bounds__(256) void attn_mfma_kernel(
    const _Float16* __restrict__ qt, const _Float16* __restrict__ kt,
    const _Float16* __restrict__ vt, _Float16* __restrict__ ctx)
{
    __shared__ _Float16 Kls[64 * 64];        // [key][d]
    __shared__ _Float16 Vls[64 * 64];        // [d][key]  (V^T)
    __shared__ _Float16 Pls[4][16 * 64];     // per-wave, swizzled

    int head = blockIdx.x, q0 = blockIdx.y * 64;
    int b = head >> 4, rh = head & 15;
    int tid = threadIdx.x, lane = tid & 63, w = tid >> 6;
    int g = lane >> 4, c = lane & 15;

    // Q fragments (A-operand): lane holds Q[q=c][d=32*ch+8*g+j]
    half8 qf[2];
    {
        const _Float16* qp = qt + ((size_t)head * S_ + q0 + w * 16 + c) * 64 + 8 * g;
        qf[0] = *(const half8*)qp;
        qf[1] = *(const half8*)(qp + 32);
    }

    floatx4 o_acc[4] = {};                   // O[q=4g+r][d=c+16t]
    float m_r[4] = {-1e30f, -1e30f, -1e30f, -1e30f};
    float l_r[4] = {0.f, 0.f, 0.f, 0.f};

    int sr = tid >> 3, sc = tid & 7;

    for (int j0 = 0; j0 < S_; j0 += 64) {
        // ---- stage K[key][d] and Vt[d][key] (8KB each), coalesced ----
#pragma unroll
        for (int i = 0; i < 2; ++i) {
            int row = sr + i * 32;
            *(float4*)(Kls + row * 64 + sc * 8) =
                *(const float4*)(kt + ((size_t)head * S_ + j0 + row) * 64 + sc * 8);
            *(float4*)(Vls + row * 64 + sc * 8) =
                *(const float4*)(vt + ((size_t)head * 64 + row) * S_ + j0 + sc * 8);
        }
        __syncthreads();

        // ---- S = Q @ K^T : 4 key-subtiles x 2 d-chunks ----
        floatx4 sacc[4] = {};
#pragma unroll
        for (int t = 0; t < 4; ++t) {
            sacc[t] = __builtin_amdgcn_mfma_f32_16x16x32_f16(
                qf[0], *(const half8*)(Kls + (t * 16 + c) * 64 + 8 * g), sacc[t], 0, 0, 0);
            sacc[t] = __builtin_amdgcn_mfma_f32_16x16x32_f16(
                qf[1], *(const half8*)(Kls + (t * 16 + c) * 64 + 32 + 8 * g), sacc[t], 0, 0, 0);
        }

        // ---- online softmax (rows q=4g+r live on the 16 lanes sharing g) --
        float corr[4], psum[4];
#pragma unroll
        for (int r = 0; r < 4; ++r) {
            float mt = fmaxf(fmaxf(sacc[0][r], sacc[1][r]),
                             fmaxf(sacc[2][r], sacc[3][r]));
#pragma unroll
            for (int off = 1; off < 16; off <<= 1)
                mt = fmaxf(mt, __shfl_xor(mt, off));
            float nm = fmaxf(m_r[r], mt);
            corr[r] = exp2f((m_r[r] - nm) * LOG2E);
            m_r[r] = nm;
            psum[r] = 0.f;
        }
#pragma unroll
        for (int t = 0; t < 4; ++t)
#pragma unroll
            for (int r = 0; r < 4; ++r) {
                float p = exp2f((sacc[t][r] - m_r[r]) * LOG2E);
                sacc[t][r] = p;
                psum[r] += p;
            }
#pragma unroll
        for (int r = 0; r < 4; ++r) {
#pragma unroll
            for (int off = 1; off < 16; off <<= 1)
                psum[r] += __shfl_xor(psum[r], off);
            l_r[r] = l_r[r] * corr[r] + psum[r];
        }
#pragma unroll
        for (int t = 0; t < 4; ++t)
#pragma unroll
            for (int r = 0; r < 4; ++r)
                o_acc[t][r] *= corr[r];

        // ---- P: C-layout -> A-layout via wave-private swizzled LDS ----
        // write: half at q*64 + (key ^ 8*(q&7));  2-deep banks (free)
#pragma unroll
        for (int t = 0; t < 4; ++t)
#pragma unroll
            for (int r = 0; r < 4; ++r) {
                int q = 4 * g + r, key = c + 16 * t;
                Pls[w][q * 64 + (key ^ (8 * (q & 7)))] = (_Float16)sacc[t][r];
            }
        half8 pf0 = *(const half8*)(Pls[w] + c * 64 + ((8 * g)      ^ (8 * (c & 7))));
        half8 pf1 = *(const half8*)(Pls[w] + c * 64 + ((32 + 8 * g) ^ (8 * (c & 7))));

        // ---- O += P @ V : 4 d-subtiles x 2 key-chunks ----
#pragma unroll
        for (int t = 0; t < 4; ++t) {
            o_acc[t] = __builtin_amdgcn_mfma_f32_16x16x32_f16(
                pf0, *(const half8*)(Vls + (t * 16 + c) * 64 + 8 * g), o_acc[t], 0, 0, 0);
            o_acc[t] = __builtin_amdgcn_mfma_f32_16x16x32_f16(
                pf1, *(const half8*)(Vls + (t * 16 + c) * 64 + 32 + 8 * g), o_acc[t], 0, 0, 0);
        }
        __syncthreads();   // protect K/V LDS before next stage
    }

    // ---- epilogue: O / l -> ctx f16 [bs][r*64+d] ----
    float inv[4];
#pragma unroll
    for (int r = 0; r < 4; ++r) inv[r] = 1.f / l_r[r];
#pragma unroll
    for (int t = 0; t < 4; ++t)
#pragma unroll
        for (int r = 0; r < 4; ++r) {
            int q = q0 + w * 16 + 4 * g + r;
            int d = c + 16 * t;
            ctx[((size_t)(b * S_ + q)) * 1024 + rh * 64 + d] =
                (_Float16)(o_acc[t][r] * inv[r]);
        }
}

// --------------------- LayerNorm in place on y[4096][1024] -----------------
__global__ __launch_bounds__(256) void ln_kernel(
    float* __restrict__ y, const float* __restrict__ g, const float* __restrict__ bb)
{
    int row = blockIdx.x, tid = threadIdx.x;
    float* p = y + (size_t)row * 1024;
    float4 v = ((const float4*)p)[tid];
    float sum = v.x + v.y + v.z + v.w;
    float sq  = v.x*v.x + v.y*v.y + v.z*v.z + v.w*v.w;
#pragma unroll
    for (int off = 32; off > 0; off >>= 1) {
        sum += __shfl_xor(sum, off);
        sq  += __shfl_xor(sq,  off);
    }
    __shared__ float rs[4], rq[4];
    int w = tid >> 6;
    if ((tid & 63) == 0) { rs[w] = sum; rq[w] = sq; }
    __syncthreads();
    sum = rs[0] + rs[1] + rs[2] + rs[3];
    sq  = rq[0] + rq[1] + rq[2] + rq[3];
    float mean = sum * (1.f / 1024.f);
    float var  = sq * (1.f / 1024.f) - mean * mean;
    float inv  = rsqrtf(var + 1e-5f);
    float4 gv = ((const float4*)g)[tid];
    float4 bv = ((const float4*)bb)[tid];
    v.x = (v.x - mean) * inv * gv.x + bv.x;
    v.y = (v.y - mean) * inv * gv.y + bv.y;
    v.z = (v.z - mean) * inv * gv.z + bv.z;
    v.w = (v.w - mean) * inv * gv.w + bv.w;
    ((float4*)p)[tid] = v;
}

// ---------------------------------------------------------------------------
extern "C" void kernel_launch(void* const* d_in, const int* in_sizes, int n_in,
                              void* d_out, int out_size, void* d_ws, size_t ws_size,
                              hipStream_t stream)
{
    const float* x     = (const float*)d_in[0];
    const float* pos   = (const float*)d_in[1];
    const float* W_qkv = (const float*)d_in[2];
    const float* b_qkv = (const float*)d_in[3];
    const float* W_out = (const float*)d_in[4];
    const float* b_out = (const float*)d_in[5];
    const float* ln_g  = (const float*)d_in[6];
    const float* ln_b  = (const float*)d_in[7];
    float* out = (float*)d_out;

    // workspace layout (96 MB total)
    char* ws = (char*)d_ws;
    _Float16* x_h    = (_Float16*)(ws);                       //  8 MB
    _Float16* wqkv_t = (_Float16*)(ws + ((size_t)8  << 20));  //  6 MB
    _Float16* wout_t = (_Float16*)(ws + ((size_t)14 << 20));  //  2 MB
    float*    qkv    = (float*)   (ws + ((size_t)16 << 20));  // 48 MB
    _Float16* qt_h   = (_Float16*)(ws + ((size_t)64 << 20));  //  8 MB
    _Float16* kt_h   = (_Float16*)(ws + ((size_t)72 << 20));  //  8 MB
    _Float16* vt_h   = (_Float16*)(ws + ((size_t)80 << 20));  //  8 MB
    _Float16* ctx_h  = (_Float16*)(ws + ((size_t)88 << 20));  //  8 MB

    // 1) casts / transposes
    cast_f16_kernel<<<4096, 256, 0, stream>>>(x, x_h, BS_ * H_);
    transpose_cast_f16<<<dim3(96, 32), 256, 0, stream>>>(W_qkv, wqkv_t, H_, NQKV);
    transpose_cast_f16<<<dim3(32, 32), 256, 0, stream>>>(W_out, wout_t, H_, H_);

    // 2) qkv = x @ W_qkv + b_qkv
    gemm_f16_mfma<<<dim3(NQKV / 128, BS_ / 128), 256, 0, stream>>>(
        x_h, wqkv_t, b_qkv, nullptr, qkv, BS_, NQKV, H_);

    // 3) k-normalize + RoPE -> f16 head-major q~, k~ ; V transpose -> f16
    rope_kernel<<<BS_ * R_ / 4, 256, 0, stream>>>(qkv, pos, qt_h, kt_h);
    vtrans_kernel<<<dim3(32, 32), 256, 0, stream>>>(qkv, vt_h);

    // 4) MFMA flash attention -> ctx f16 [bs][1024]
    attn_mfma_kernel<<<dim3(32, 32), 256, 0, stream>>>(qt_h, kt_h, vt_h, ctx_h);

    // 5) out proj + bias + residual -> d_out (fp32)
    gemm_f16_mfma<<<dim3(H_ / 128, BS_ / 128), 256, 0, stream>>>(
        ctx_h, wout_t, b_out, x, out, BS_, H_, H_);

    // 6) LayerNorm in place
    ln_kernel<<<BS_, 256, 0, stream>>>(out, ln_g, ln_b);
}

// Round 4
// 275.595 us; speedup vs baseline: 4.6710x; 1.2544x over previous
//
#include <hip/hip_runtime.h>

// ---------------------------------------------------------------------------
// SelfMultiHeadAttn: x[B,S,H] -> LN(x + OutProj(SDPA(RoPE(q), RoPE(k/|k|), v)))
// B=2 S=2048 H=1024 R=16 heads, K=64 head dim. fp32 in/out.
// R4 (= R3 + compile fix): transposed flash attention (S^T = K@Q^T,
//     O^T = V^T@P^T; P^T B-frag == packed exp registers, no cross-lane
//     transform), XOR-swizzled LDS, global_load_lds(16B) staging everywhere.
// ---------------------------------------------------------------------------

#define B_   2
#define S_   2048
#define H_   1024
#define R_   16
#define BS_  (B_*S_)     // 4096 rows
#define NQKV 3072        // R*K*3
#define LOG2E 1.44269504088896f

typedef float    floatx4 __attribute__((ext_vector_type(4)));
typedef _Float16 half8   __attribute__((ext_vector_type(8)));
typedef _Float16 half4   __attribute__((ext_vector_type(4)));
typedef __fp16   fp16x2  __attribute__((ext_vector_type(2)));  // cvt_pkrtz ret

// async global -> LDS, 16 B per lane (lds dest = wave-uniform base + lane*16)
__device__ __forceinline__ void gl_lds16(const _Float16* g, _Float16* l) {
    __builtin_amdgcn_global_load_lds(
        (const __attribute__((address_space(1))) unsigned int*)g,
        (__attribute__((address_space(3))) unsigned int*)l, 16, 0, 0);
}

// ---------------- cast fp32 -> fp16 (vectorized, n % 1024 == 0) ------------
__global__ __launch_bounds__(256) void cast_f16_kernel(
    const float* __restrict__ in, _Float16* __restrict__ out, int n)
{
    int i = (blockIdx.x * 256 + threadIdx.x) * 4;
    if (i >= n) return;
    float4 v = *(const float4*)(in + i);
    half4 h;
    h.x = (_Float16)v.x; h.y = (_Float16)v.y; h.z = (_Float16)v.z; h.w = (_Float16)v.w;
    *(half4*)(out + i) = h;
}

// --------- transpose + cast: in[rows][cols] f32 -> out[cols][rows] f16 -----
__global__ __launch_bounds__(256) void transpose_cast_f16(
    const float* __restrict__ in, _Float16* __restrict__ out, int rows, int cols)
{
    __shared__ float tile[32][33];
    int bx = blockIdx.x * 32;
    int by = blockIdx.y * 32;
    int tx = threadIdx.x & 31, ty = threadIdx.x >> 5;
#pragma unroll
    for (int i = 0; i < 32; i += 8)
        tile[ty + i][tx] = in[(size_t)(by + ty + i) * cols + bx + tx];
    __syncthreads();
#pragma unroll
    for (int i = 0; i < 32; i += 8)
        out[(size_t)(bx + ty + i) * rows + by + tx] = (_Float16)tile[tx][ty + i];
}

// ------------------- f16 MFMA GEMM:  C = A @ Bt^T + bias (+resid) ----------
// m97 pattern: global_load_lds width-16 staging, 2-barrier K-loop.
//   A: lane holds A[m=lane&15][k = 8*(lane>>4) + j]
//   B: lane holds B[k = 8*(lane>>4) + j][n=lane&15]   (reads Bt[n][k] contig)
//   D: reg r holds D[row = 4*(lane>>4) + r][col = lane&15]
__global__ __launch_bounds__(256) void gemm_f16_mfma(
    const _Float16* __restrict__ A, const _Float16* __restrict__ Bt,
    const float* __restrict__ bias, const float* __restrict__ resid,
    float* __restrict__ C, int M, int N, int Kd)
{
    __shared__ _Float16 Als[128 * 32];
    __shared__ _Float16 Bls[128 * 32];
    int tid  = threadIdx.x;
    int lane = tid & 63, w = tid >> 6;
    int wr = w >> 1, wc = w & 1;
    int fr = lane & 15, fq = lane >> 4;
    int m0 = blockIdx.y * 128, n0 = blockIdx.x * 128;

    floatx4 acc[4][4] = {};

    // staging: wave w stages chunks {2w, 2w+1} of A and B (1KB each:
    // 16 rows x 32 halves; lane L -> row ch*16+(L>>2), col (L&3)*8; LDS
    // offset = ch*1KB + L*16B -> uniform base + lane*16).
    const _Float16* ga[2]; const _Float16* gb[2];
    _Float16 *la[2], *lb[2];
#pragma unroll
    for (int i2 = 0; i2 < 2; ++i2) {
        int ch = 2 * w + i2;
        int row = ch * 16 + (lane >> 2), col = (lane & 3) * 8;
        ga[i2] = A  + (size_t)(m0 + row) * Kd + col;
        gb[i2] = Bt + (size_t)(n0 + row) * Kd + col;
        la[i2] = Als + ch * 512;
        lb[i2] = Bls + ch * 512;
    }

    for (int k0 = 0; k0 < Kd; k0 += 32) {
        __syncthreads();                       // prev iter's frag reads done
#pragma unroll
        for (int i2 = 0; i2 < 2; ++i2) {
            gl_lds16(ga[i2] + k0, la[i2]);
            gl_lds16(gb[i2] + k0, lb[i2]);
        }
        __syncthreads();                       // vmcnt drained -> LDS ready
        half8 af[4], bf[4];
#pragma unroll
        for (int i = 0; i < 4; ++i)
            af[i] = *(const half8*)(Als + (wr * 64 + i * 16 + fr) * 32 + fq * 8);
#pragma unroll
        for (int j = 0; j < 4; ++j)
            bf[j] = *(const half8*)(Bls + (wc * 64 + j * 16 + fr) * 32 + fq * 8);
#pragma unroll
        for (int i = 0; i < 4; ++i)
#pragma unroll
            for (int j = 0; j < 4; ++j)
                acc[i][j] = __builtin_amdgcn_mfma_f32_16x16x32_f16(
                    af[i], bf[j], acc[i][j], 0, 0, 0);
    }

#pragma unroll
    for (int i = 0; i < 4; ++i)
#pragma unroll
        for (int j = 0; j < 4; ++j)
#pragma unroll
            for (int r2 = 0; r2 < 4; ++r2) {
                int row = m0 + wr * 64 + i * 16 + fq * 4 + r2;
                int col = n0 + wc * 64 + j * 16 + fr;
                float v = acc[i][j][r2] + bias[col];
                if (resid) v += resid[(size_t)row * N + col];
                C[(size_t)row * N + col] = v;
            }
}

// ---------- k-normalize + RoPE for q,k; write head-major f16 q~,k~ ---------
__global__ __launch_bounds__(256) void rope_kernel(
    const float* __restrict__ qkv, const float* __restrict__ pos,
    _Float16* __restrict__ qt, _Float16* __restrict__ kt)
{
    int task = blockIdx.x * 4 + (threadIdx.x >> 6);   // bs*16 + r
    int lane = threadIdx.x & 63;
    int r = task & 15, bs = task >> 4;
    int b = bs >> 11, s = bs & 2047;

    const float* base = qkv + (size_t)bs * NQKV + r * 192;
    float qv = base[lane];
    float kv = base[64 + lane];

    float ss = kv * kv;
#pragma unroll
    for (int off = 32; off > 0; off >>= 1) ss += __shfl_xor(ss, off);
    kv *= rsqrtf(ss);

    int j = lane & 31;
    float sn = pos[(size_t)bs * 64 + j];
    float cs = pos[(size_t)bs * 64 + 32 + j];
    float qp = __shfl_xor(qv, 32);
    float kp = __shfl_xor(kv, 32);
    float qo, ko;
    if (lane < 32) { qo = qv * cs - qp * sn; ko = kv * cs - kp * sn; }
    else           { qo = qp * sn + qv * cs; ko = kp * sn + kv * cs; }

    size_t oidx = ((size_t)(b * 16 + r) * S_ + s) * 64 + lane;
    qt[oidx] = (_Float16)qo;
    kt[oidx] = (_Float16)ko;
}

// ------- V transpose into pre-baked attention LDS image -----------------
// vt2[head][tau][d][P]: position P of row d holds V[key = s0 + key_of(P,d)][d]
// where  op=P>>3, ol=op^(d&7), kappa=ol>>2, glog=ol&3,
//        key_of = 32*kappa + 16*((P>>2)&1) + 4*glog + (P&3).
// This bakes both the PV keymap permutation and the bank XOR swizzle.
__global__ __launch_bounds__(256) void vtrans_kernel(
    const float* __restrict__ qkv, _Float16* __restrict__ vt2)
{
    __shared__ float tile[64][65];
    int head = blockIdx.x, tau = blockIdx.y;
    int s0 = tau * 64;
    int b = head >> 4, rh = head & 15;
    int tx = threadIdx.x & 63, ty = threadIdx.x >> 6;
#pragma unroll
    for (int si = ty; si < 64; si += 4)
        tile[si][tx] = qkv[(size_t)(b * S_ + s0 + si) * NQKV + rh * 192 + 128 + tx];
    __syncthreads();
    int P = tx;
    int op = P >> 3;
    int hi = (P >> 2) & 1, lo = P & 3;
#pragma unroll
    for (int d = ty; d < 64; d += 4) {
        int ol = op ^ (d & 7);
        int key = 32 * (ol >> 2) + 16 * hi + 4 * (ol & 3) + lo;
        vt2[(((size_t)head * 32 + tau) * 64 + d) * 64 + P] = (_Float16)tile[key][d];
    }
}

// ------------------- transposed MFMA flash attention -----------------------
// grid (32 heads, 32 q-tiles), block 256 = 4 waves; wave w owns queries
// q0+w*16+c (one per lane-column c). Per 64-key tile:
//   S^T = K @ Q^T  (8 MFMAs; sacc[t][r] = S[q=c][key=16t+4g+r])
//   per-lane softmax (2 shfl reductions), P packed in-register -> B-frag
//   O^T += V^T @ P^T (8 MFMAs; o_acc[t][r] = O[q=c][d=16t+4g+r])
__global__ __launch_bounds__(256) void attn_mfma_kernel(
    const _Float16* __restrict__ qt, const _Float16* __restrict__ kt,
    const _Float16* __restrict__ vt2, _Float16* __restrict__ ctx)
{
    __shared__ _Float16 Kls[64 * 64];
    __shared__ _Float16 Vls[64 * 64];

    int head = blockIdx.x, q0 = blockIdx.y * 64;
    int b = head >> 4, rh = head & 15;
    int tid = threadIdx.x, lane = tid & 63, w = tid >> 6;
    int g = lane >> 4, c = lane & 15;

    // Q B-frags: lane(g,c) chunk kap holds Q[q=c][d=32*kap+8g+j]
    half8 qf[2];
    {
        const _Float16* qp = qt + ((size_t)head * S_ + q0 + w * 16 + c) * 64 + 8 * g;
        qf[0] = *(const half8*)qp;
        qf[1] = *(const half8*)(qp + 32);
    }

    floatx4 o_acc[4] = {};
    float m_s = -1e30f, l_s = 0.f;

    // staging: wave w stages K chunks {2w,2w+1} and V chunks {2w,2w+1}
    // (1KB each). K: lane L -> row ch*8+(L>>3), d-octet (L&7)^(L>>3)
    // (XOR swizzle via global source address; coalescing unaffected).
    // V: vt2 is already the LDS image -> linear copy.
    const _Float16* kg[2]; const _Float16* vg[2];
    _Float16 *kl_[2], *vl_[2];
#pragma unroll
    for (int i2 = 0; i2 < 2; ++i2) {
        int ch = 2 * w + i2;
        int krow = ch * 8 + (lane >> 3);
        int koct = (lane & 7) ^ (lane >> 3);
        kg[i2] = kt + ((size_t)head * S_ + krow) * 64 + koct * 8;
        kl_[i2] = Kls + ch * 512;
        vg[i2] = vt2 + ((size_t)head * 32) * 4096 + ch * 512 + lane * 8;
        vl_[i2] = Vls + ch * 512;
    }

    int co = c & 7;   // XOR swizzle term for frag reads

    for (int j0 = 0; j0 < S_; j0 += 64) {
        __syncthreads();                       // prev tile's frag reads done
#pragma unroll
        for (int i2 = 0; i2 < 2; ++i2) {
            gl_lds16(kg[i2] + (size_t)j0 * 64, kl_[i2]);
            gl_lds16(vg[i2] + (size_t)(j0 >> 6) * 4096, vl_[i2]);
        }
        __syncthreads();                       // vmcnt drained -> LDS ready

        // ---- S^T = K @ Q^T ----
        floatx4 sacc[4];
#pragma unroll
        for (int t = 0; t < 4; ++t) {
            floatx4 z = {};
            const _Float16* krow = Kls + (16 * t + c) * 64;
            z = __builtin_amdgcn_mfma_f32_16x16x32_f16(
                *(const half8*)(krow + ((g) ^ co) * 8), qf[0], z, 0, 0, 0);
            z = __builtin_amdgcn_mfma_f32_16x16x32_f16(
                *(const half8*)(krow + ((4 + g) ^ co) * 8), qf[1], z, 0, 0, 0);
            sacc[t] = z;
        }

        // ---- per-lane online softmax (one query per lane) ----
        float mt = fmaxf(fmaxf(fmaxf(sacc[0][0], sacc[0][1]), fmaxf(sacc[0][2], sacc[0][3])),
                   fmaxf(fmaxf(sacc[1][0], sacc[1][1]), fmaxf(sacc[1][2], sacc[1][3])));
        mt = fmaxf(mt,
             fmaxf(fmaxf(fmaxf(sacc[2][0], sacc[2][1]), fmaxf(sacc[2][2], sacc[2][3])),
                   fmaxf(fmaxf(sacc[3][0], sacc[3][1]), fmaxf(sacc[3][2], sacc[3][3]))));
        mt = fmaxf(mt, __shfl_xor(mt, 16));
        mt = fmaxf(mt, __shfl_xor(mt, 32));
        float nm = fmaxf(m_s, mt);
        float corr = exp2f((m_s - nm) * LOG2E);
        m_s = nm;
        float mL = nm * LOG2E;
        float ps = 0.f;
#pragma unroll
        for (int t = 0; t < 4; ++t)
#pragma unroll
            for (int r = 0; r < 4; ++r) {
                float p = exp2f(sacc[t][r] * LOG2E - mL);
                sacc[t][r] = p;
                ps += p;
            }
        ps += __shfl_xor(ps, 16);
        ps += __shfl_xor(ps, 32);
        l_s = l_s * corr + ps;
#pragma unroll
        for (int t = 0; t < 4; ++t)
#pragma unroll
            for (int r = 0; r < 4; ++r)
                o_acc[t][r] *= corr;

        // ---- pack P -> B-frags (register-only; keymap matches vt2) ----
        union { half8 v; fp16x2 h2[4]; } pf0, pf1;
        pf0.h2[0] = __builtin_amdgcn_cvt_pkrtz(sacc[0][0], sacc[0][1]);
        pf0.h2[1] = __builtin_amdgcn_cvt_pkrtz(sacc[0][2], sacc[0][3]);
        pf0.h2[2] = __builtin_amdgcn_cvt_pkrtz(sacc[1][0], sacc[1][1]);
        pf0.h2[3] = __builtin_amdgcn_cvt_pkrtz(sacc[1][2], sacc[1][3]);
        pf1.h2[0] = __builtin_amdgcn_cvt_pkrtz(sacc[2][0], sacc[2][1]);
        pf1.h2[1] = __builtin_amdgcn_cvt_pkrtz(sacc[2][2], sacc[2][3]);
        pf1.h2[2] = __builtin_amdgcn_cvt_pkrtz(sacc[3][0], sacc[3][1]);
        pf1.h2[3] = __builtin_amdgcn_cvt_pkrtz(sacc[3][2], sacc[3][3]);

        // ---- O^T += V^T @ P^T ----
#pragma unroll
        for (int t = 0; t < 4; ++t) {
            const _Float16* vrow = Vls + (16 * t + c) * 64;
            o_acc[t] = __builtin_amdgcn_mfma_f32_16x16x32_f16(
                *(const half8*)(vrow + ((g) ^ co) * 8), pf0.v, o_acc[t], 0, 0, 0);
            o_acc[t] = __builtin_amdgcn_mfma_f32_16x16x32_f16(
                *(const half8*)(vrow + ((4 + g) ^ co) * 8), pf1.v, o_acc[t], 0, 0, 0);
        }
    }

    // ---- epilogue: O[q=c][d=16t+4g+r] / l -> ctx f16 [bs][rh*64+d] ----
    float inv = 1.f / l_s;
    size_t rowbase = ((size_t)(b * S_ + q0 + w * 16 + c)) * 1024 + rh * 64;
#pragma unroll
    for (int t = 0; t < 4; ++t) {
        union { half4 v; fp16x2 h2[2]; } e;
        e.h2[0] = __builtin_amdgcn_cvt_pkrtz(o_acc[t][0] * inv, o_acc[t][1] * inv);
        e.h2[1] = __builtin_amdgcn_cvt_pkrtz(o_acc[t][2] * inv, o_acc[t][3] * inv);
        *(half4*)(ctx + rowbase + 16 * t + 4 * g) = e.v;
    }
}

// --------------------- LayerNorm in place on y[4096][1024] -----------------
__global__ __launch_bounds__(256) void ln_kernel(
    float* __restrict__ y, const float* __restrict__ g, const float* __restrict__ bb)
{
    int row = blockIdx.x, tid = threadIdx.x;
    float* p = y + (size_t)row * 1024;
    float4 v = ((const float4*)p)[tid];
    float sum = v.x + v.y + v.z + v.w;
    float sq  = v.x*v.x + v.y*v.y + v.z*v.z + v.w*v.w;
#pragma unroll
    for (int off = 32; off > 0; off >>= 1) {
        sum += __shfl_xor(sum, off);
        sq  += __shfl_xor(sq,  off);
    }
    __shared__ float rs[4], rq[4];
    int w = tid >> 6;
    if ((tid & 63) == 0) { rs[w] = sum; rq[w] = sq; }
    __syncthreads();
    sum = rs[0] + rs[1] + rs[2] + rs[3];
    sq  = rq[0] + rq[1] + rq[2] + rq[3];
    float mean = sum * (1.f / 1024.f);
    float var  = sq * (1.f / 1024.f) - mean * mean;
    float inv  = rsqrtf(var + 1e-5f);
    float4 gv = ((const float4*)g)[tid];
    float4 bv = ((const float4*)bb)[tid];
    v.x = (v.x - mean) * inv * gv.x + bv.x;
    v.y = (v.y - mean) * inv * gv.y + bv.y;
    v.z = (v.z - mean) * inv * gv.z + bv.z;
    v.w = (v.w - mean) * inv * gv.w + bv.w;
    ((float4*)p)[tid] = v;
}

// ---------------------------------------------------------------------------
extern "C" void kernel_launch(void* const* d_in, const int* in_sizes, int n_in,
                              void* d_out, int out_size, void* d_ws, size_t ws_size,
                              hipStream_t stream)
{
    const float* x     = (const float*)d_in[0];
    const float* pos   = (const float*)d_in[1];
    const float* W_qkv = (const float*)d_in[2];
    const float* b_qkv = (const float*)d_in[3];
    const float* W_out = (const float*)d_in[4];
    const float* b_out = (const float*)d_in[5];
    const float* ln_g  = (const float*)d_in[6];
    const float* ln_b  = (const float*)d_in[7];
    float* out = (float*)d_out;

    char* ws = (char*)d_ws;
    _Float16* x_h    = (_Float16*)(ws);                       //  8 MB
    _Float16* wqkv_t = (_Float16*)(ws + ((size_t)8  << 20));  //  6 MB
    _Float16* wout_t = (_Float16*)(ws + ((size_t)14 << 20));  //  2 MB
    float*    qkv    = (float*)   (ws + ((size_t)16 << 20));  // 48 MB
    _Float16* qt_h   = (_Float16*)(ws + ((size_t)64 << 20));  //  8 MB
    _Float16* kt_h   = (_Float16*)(ws + ((size_t)72 << 20));  //  8 MB
    _Float16* vt2_h  = (_Float16*)(ws + ((size_t)80 << 20));  //  8 MB
    _Float16* ctx_h  = (_Float16*)(ws + ((size_t)88 << 20));  //  8 MB

    cast_f16_kernel<<<4096, 256, 0, stream>>>(x, x_h, BS_ * H_);
    transpose_cast_f16<<<dim3(96, 32), 256, 0, stream>>>(W_qkv, wqkv_t, H_, NQKV);
    transpose_cast_f16<<<dim3(32, 32), 256, 0, stream>>>(W_out, wout_t, H_, H_);

    gemm_f16_mfma<<<dim3(NQKV / 128, BS_ / 128), 256, 0, stream>>>(
        x_h, wqkv_t, b_qkv, nullptr, qkv, BS_, NQKV, H_);

    rope_kernel<<<BS_ * R_ / 4, 256, 0, stream>>>(qkv, pos, qt_h, kt_h);
    vtrans_kernel<<<dim3(32, 32), 256, 0, stream>>>(qkv, vt2_h);

    attn_mfma_kernel<<<dim3(32, 32), 256, 0, stream>>>(qt_h, kt_h, vt2_h, ctx_h);

    gemm_f16_mfma<<<dim3(H_ / 128, BS_ / 128), 256, 0, stream>>>(
        ctx_h, wout_t, b_out, x, out, BS_, H_, H_);

    ln_kernel<<<BS_, 256, 0, stream>>>(out, ln_g, ln_b);
}

// Round 5
// 236.690 us; speedup vs baseline: 5.4387x; 1.1644x over previous
//
#include <hip/hip_runtime.h>

// ---------------------------------------------------------------------------
// SelfMultiHeadAttn: x[B,S,H] -> LN(x + OutProj(SDPA(RoPE(q), RoPE(k/|k|), v)))
// B=2 S=2048 H=1024 R=16 heads, K=64 head dim. fp32 in/out.
// R5: attention = static-max softmax (s <= |q~| since |k^|=1), raw v_exp_f32,
//     LOG2E folded into q~ at RoPE, 2 q-groups/wave (128q blocks) to halve
//     LDS fragment reads. XOR-swizzled LDS, global_load_lds(16B) staging.
// ---------------------------------------------------------------------------

#define B_   2
#define S_   2048
#define H_   1024
#define R_   16
#define BS_  (B_*S_)     // 4096 rows
#define NQKV 3072        // R*K*3
#define LOG2E 1.44269504088896f

typedef float    floatx4 __attribute__((ext_vector_type(4)));
typedef _Float16 half8   __attribute__((ext_vector_type(8)));
typedef _Float16 half4   __attribute__((ext_vector_type(4)));
typedef __fp16   fp16x2  __attribute__((ext_vector_type(2)));  // cvt_pkrtz ret

#if __has_builtin(__builtin_amdgcn_exp2f)
#define EXP2(x) __builtin_amdgcn_exp2f(x)
#else
#define EXP2(x) exp2f(x)
#endif

// async global -> LDS, 16 B per lane (lds dest = wave-uniform base + lane*16)
__device__ __forceinline__ void gl_lds16(const _Float16* g, _Float16* l) {
    __builtin_amdgcn_global_load_lds(
        (const __attribute__((address_space(1))) unsigned int*)g,
        (__attribute__((address_space(3))) unsigned int*)l, 16, 0, 0);
}

// ---------------- cast fp32 -> fp16 (vectorized, n % 1024 == 0) ------------
__global__ __launch_bounds__(256) void cast_f16_kernel(
    const float* __restrict__ in, _Float16* __restrict__ out, int n)
{
    int i = (blockIdx.x * 256 + threadIdx.x) * 4;
    if (i >= n) return;
    float4 v = *(const float4*)(in + i);
    half4 h;
    h.x = (_Float16)v.x; h.y = (_Float16)v.y; h.z = (_Float16)v.z; h.w = (_Float16)v.w;
    *(half4*)(out + i) = h;
}

// --------- transpose + cast: in[rows][cols] f32 -> out[cols][rows] f16 -----
__global__ __launch_bounds__(256) void transpose_cast_f16(
    const float* __restrict__ in, _Float16* __restrict__ out, int rows, int cols)
{
    __shared__ float tile[32][33];
    int bx = blockIdx.x * 32;
    int by = blockIdx.y * 32;
    int tx = threadIdx.x & 31, ty = threadIdx.x >> 5;
#pragma unroll
    for (int i = 0; i < 32; i += 8)
        tile[ty + i][tx] = in[(size_t)(by + ty + i) * cols + bx + tx];
    __syncthreads();
#pragma unroll
    for (int i = 0; i < 32; i += 8)
        out[(size_t)(bx + ty + i) * rows + by + tx] = (_Float16)tile[tx][ty + i];
}

// ------------------- f16 MFMA GEMM:  C = A @ Bt^T + bias (+resid) ----------
// m97 pattern: global_load_lds width-16 staging, 2-barrier K-loop.
//   A: lane holds A[m=lane&15][k = 8*(lane>>4) + j]
//   B: lane holds B[k = 8*(lane>>4) + j][n=lane&15]   (reads Bt[n][k] contig)
//   D: reg r holds D[row = 4*(lane>>4) + r][col = lane&15]
__global__ __launch_bounds__(256) void gemm_f16_mfma(
    const _Float16* __restrict__ A, const _Float16* __restrict__ Bt,
    const float* __restrict__ bias, const float* __restrict__ resid,
    float* __restrict__ C, int M, int N, int Kd)
{
    __shared__ _Float16 Als[128 * 32];
    __shared__ _Float16 Bls[128 * 32];
    int tid  = threadIdx.x;
    int lane = tid & 63, w = tid >> 6;
    int wr = w >> 1, wc = w & 1;
    int fr = lane & 15, fq = lane >> 4;
    int m0 = blockIdx.y * 128, n0 = blockIdx.x * 128;

    floatx4 acc[4][4] = {};

    const _Float16* ga[2]; const _Float16* gb[2];
    _Float16 *la[2], *lb[2];
#pragma unroll
    for (int i2 = 0; i2 < 2; ++i2) {
        int ch = 2 * w + i2;
        int row = ch * 16 + (lane >> 2), col = (lane & 3) * 8;
        ga[i2] = A  + (size_t)(m0 + row) * Kd + col;
        gb[i2] = Bt + (size_t)(n0 + row) * Kd + col;
        la[i2] = Als + ch * 512;
        lb[i2] = Bls + ch * 512;
    }

    for (int k0 = 0; k0 < Kd; k0 += 32) {
        __syncthreads();
#pragma unroll
        for (int i2 = 0; i2 < 2; ++i2) {
            gl_lds16(ga[i2] + k0, la[i2]);
            gl_lds16(gb[i2] + k0, lb[i2]);
        }
        __syncthreads();
        half8 af[4], bf[4];
#pragma unroll
        for (int i = 0; i < 4; ++i)
            af[i] = *(const half8*)(Als + (wr * 64 + i * 16 + fr) * 32 + fq * 8);
#pragma unroll
        for (int j = 0; j < 4; ++j)
            bf[j] = *(const half8*)(Bls + (wc * 64 + j * 16 + fr) * 32 + fq * 8);
#pragma unroll
        for (int i = 0; i < 4; ++i)
#pragma unroll
            for (int j = 0; j < 4; ++j)
                acc[i][j] = __builtin_amdgcn_mfma_f32_16x16x32_f16(
                    af[i], bf[j], acc[i][j], 0, 0, 0);
    }

#pragma unroll
    for (int i = 0; i < 4; ++i)
#pragma unroll
        for (int j = 0; j < 4; ++j)
#pragma unroll
            for (int r2 = 0; r2 < 4; ++r2) {
                int row = m0 + wr * 64 + i * 16 + fq * 4 + r2;
                int col = n0 + wc * 64 + j * 16 + fr;
                float v = acc[i][j][r2] + bias[col];
                if (resid) v += resid[(size_t)row * N + col];
                C[(size_t)row * N + col] = v;
            }
}

// ---------- k-normalize + RoPE; q~ pre-scaled by LOG2E; f16 head-major -----
__global__ __launch_bounds__(256) void rope_kernel(
    const float* __restrict__ qkv, const float* __restrict__ pos,
    _Float16* __restrict__ qt, _Float16* __restrict__ kt)
{
    int task = blockIdx.x * 4 + (threadIdx.x >> 6);   // bs*16 + r
    int lane = threadIdx.x & 63;
    int r = task & 15, bs = task >> 4;
    int b = bs >> 11, s = bs & 2047;

    const float* base = qkv + (size_t)bs * NQKV + r * 192;
    float qv = base[lane];
    float kv = base[64 + lane];

    float ss = kv * kv;
#pragma unroll
    for (int off = 32; off > 0; off >>= 1) ss += __shfl_xor(ss, off);
    kv *= rsqrtf(ss);

    int j = lane & 31;
    float sn = pos[(size_t)bs * 64 + j];
    float cs = pos[(size_t)bs * 64 + 32 + j];
    float qp = __shfl_xor(qv, 32);
    float kp = __shfl_xor(kv, 32);
    float qo, ko;
    if (lane < 32) { qo = qv * cs - qp * sn; ko = kv * cs - kp * sn; }
    else           { qo = qp * sn + qv * cs; ko = kp * sn + kv * cs; }

    size_t oidx = ((size_t)(b * 16 + r) * S_ + s) * 64 + lane;
    qt[oidx] = (_Float16)(qo * LOG2E);   // fold log2(e) into q~
    kt[oidx] = (_Float16)ko;
}

// ------- V transpose into pre-baked attention LDS image -----------------
// vt2[head][tau][d][P]: position P of row d holds V[key = s0 + key_of(P,d)][d]
// op=P>>3, ol=op^(d&7):  key_of = 32*(ol>>2) + 16*((P>>2)&1) + 4*(ol&3) + (P&3)
// (bakes the PV keymap permutation and the bank XOR swizzle).
__global__ __launch_bounds__(256) void vtrans_kernel(
    const float* __restrict__ qkv, _Float16* __restrict__ vt2)
{
    __shared__ float tile[64][65];
    int head = blockIdx.x, tau = blockIdx.y;
    int s0 = tau * 64;
    int b = head >> 4, rh = head & 15;
    int tx = threadIdx.x & 63, ty = threadIdx.x >> 6;
#pragma unroll
    for (int si = ty; si < 64; si += 4)
        tile[si][tx] = qkv[(size_t)(b * S_ + s0 + si) * NQKV + rh * 192 + 128 + tx];
    __syncthreads();
    int P = tx;
    int op = P >> 3;
    int hi = (P >> 2) & 1, lo = P & 3;
#pragma unroll
    for (int d = ty; d < 64; d += 4) {
        int ol = op ^ (d & 7);
        int key = 32 * (ol >> 2) + 16 * hi + 4 * (ol & 3) + lo;
        vt2[(((size_t)head * 32 + tau) * 64 + d) * 64 + P] = (_Float16)tile[key][d];
    }
}

// ------------------- transposed MFMA flash attention -----------------------
// grid (32 heads, 16 q-tiles of 128), block 256 = 4 waves; wave w owns 32
// queries as 2 q-groups of 16 (one query per lane-column c). Per 64-key tile:
//   kfr = K frags (8 ds_read_b128, shared by both q-groups)
//   S^T = K @ Q~^T (log2-scaled), p = exp2(s - |q~|) (static max), l partial
//   vfr = V frags (8 reads, shared);  O^T += V^T @ P^T
__global__ __launch_bounds__(256) void attn_mfma_kernel(
    const _Float16* __restrict__ qt, const _Float16* __restrict__ kt,
    const _Float16* __restrict__ vt2, _Float16* __restrict__ ctx)
{
    __shared__ _Float16 Kls[64 * 64];
    __shared__ _Float16 Vls[64 * 64];

    int head = blockIdx.x, q0 = blockIdx.y * 128;
    int b = head >> 4, rh = head & 15;
    int tid = threadIdx.x, lane = tid & 63, w = tid >> 6;
    int g = lane >> 4, c = lane & 15;

    // Q B-frags + static softmax bound mL = |q~| (log2 units) per q-group
    half8 qf[2][2];
    float mL[2], l_s[2] = {0.f, 0.f};
#pragma unroll
    for (int qg = 0; qg < 2; ++qg) {
        const _Float16* qp =
            qt + ((size_t)head * S_ + q0 + w * 32 + qg * 16 + c) * 64 + 8 * g;
        qf[qg][0] = *(const half8*)qp;
        qf[qg][1] = *(const half8*)(qp + 32);
        float qq = 0.f;
#pragma unroll
        for (int i = 0; i < 8; ++i) {
            float a = (float)qf[qg][0][i], b2 = (float)qf[qg][1][i];
            qq += a * a + b2 * b2;
        }
        qq += __shfl_xor(qq, 16);
        qq += __shfl_xor(qq, 32);
        mL[qg] = sqrtf(qq);       // s_log2 <= |q~|*|k^| = mL  (k^ unit norm)
    }

    floatx4 o_acc[2][4] = {};

    // staging (per wave: K chunks {2w,2w+1}, V chunks {2w,2w+1}, 1KB each).
    // K: lane L -> row ch*8+(L>>3), d-octet (L&7)^(L>>3)  (XOR swizzle via
    // global source address). V: vt2 is already the LDS image -> linear copy.
    const _Float16* kg[2]; const _Float16* vg[2];
    _Float16 *kl_[2], *vl_[2];
#pragma unroll
    for (int i2 = 0; i2 < 2; ++i2) {
        int ch = 2 * w + i2;
        int krow = ch * 8 + (lane >> 3);
        int koct = (lane & 7) ^ (lane >> 3);
        kg[i2] = kt + ((size_t)head * S_ + krow) * 64 + koct * 8;
        kl_[i2] = Kls + ch * 512;
        vg[i2] = vt2 + ((size_t)head * 32) * 4096 + ch * 512 + lane * 8;
        vl_[i2] = Vls + ch * 512;
    }

    int co = c & 7;   // XOR swizzle term for frag reads

    for (int j0 = 0; j0 < S_; j0 += 64) {
        __syncthreads();                       // prev tile's frag reads done
#pragma unroll
        for (int i2 = 0; i2 < 2; ++i2) {
            gl_lds16(kg[i2] + (size_t)j0 * 64, kl_[i2]);
            gl_lds16(vg[i2] + (size_t)(j0 >> 6) * 4096, vl_[i2]);
        }
        __syncthreads();                       // vmcnt drained -> LDS ready

        // ---- K fragments once, shared by both q-groups ----
        half8 kfr[8];
#pragma unroll
        for (int t = 0; t < 4; ++t) {
            const _Float16* krow = Kls + (16 * t + c) * 64;
            kfr[2 * t]     = *(const half8*)(krow + ((g) ^ co) * 8);
            kfr[2 * t + 1] = *(const half8*)(krow + ((4 + g) ^ co) * 8);
        }

        union { half8 v; fp16x2 h2[4]; } pf[2][2];
#pragma unroll
        for (int qg = 0; qg < 2; ++qg) {
            // S^T = K @ Q~^T  (result already in log2 units)
            floatx4 sacc[4];
#pragma unroll
            for (int t = 0; t < 4; ++t) {
                floatx4 z = {};
                z = __builtin_amdgcn_mfma_f32_16x16x32_f16(
                    kfr[2 * t], qf[qg][0], z, 0, 0, 0);
                z = __builtin_amdgcn_mfma_f32_16x16x32_f16(
                    kfr[2 * t + 1], qf[qg][1], z, 0, 0, 0);
                sacc[t] = z;
            }
            // static-max softmax: p = exp2(s - mL); l accumulates per-lane
            float mLq = mL[qg], ps = 0.f;
#pragma unroll
            for (int t = 0; t < 4; ++t)
#pragma unroll
                for (int r = 0; r < 4; ++r) {
                    float p = EXP2(sacc[t][r] - mLq);
                    sacc[t][r] = p;
                    ps += p;
                }
            l_s[qg] += ps;
            pf[qg][0].h2[0] = __builtin_amdgcn_cvt_pkrtz(sacc[0][0], sacc[0][1]);
            pf[qg][0].h2[1] = __builtin_amdgcn_cvt_pkrtz(sacc[0][2], sacc[0][3]);
            pf[qg][0].h2[2] = __builtin_amdgcn_cvt_pkrtz(sacc[1][0], sacc[1][1]);
            pf[qg][0].h2[3] = __builtin_amdgcn_cvt_pkrtz(sacc[1][2], sacc[1][3]);
            pf[qg][1].h2[0] = __builtin_amdgcn_cvt_pkrtz(sacc[2][0], sacc[2][1]);
            pf[qg][1].h2[1] = __builtin_amdgcn_cvt_pkrtz(sacc[2][2], sacc[2][3]);
            pf[qg][1].h2[2] = __builtin_amdgcn_cvt_pkrtz(sacc[3][0], sacc[3][1]);
            pf[qg][1].h2[3] = __builtin_amdgcn_cvt_pkrtz(sacc[3][2], sacc[3][3]);
        }

        // ---- V fragments once, shared; O^T += V^T @ P^T ----
#pragma unroll
        for (int t = 0; t < 4; ++t) {
            const _Float16* vrow = Vls + (16 * t + c) * 64;
            half8 v0 = *(const half8*)(vrow + ((g) ^ co) * 8);
            half8 v1 = *(const half8*)(vrow + ((4 + g) ^ co) * 8);
#pragma unroll
            for (int qg = 0; qg < 2; ++qg) {
                o_acc[qg][t] = __builtin_amdgcn_mfma_f32_16x16x32_f16(
                    v0, pf[qg][0].v, o_acc[qg][t], 0, 0, 0);
                o_acc[qg][t] = __builtin_amdgcn_mfma_f32_16x16x32_f16(
                    v1, pf[qg][1].v, o_acc[qg][t], 0, 0, 0);
            }
        }
    }

    // ---- epilogue: l = full sum (per-lane partials over g), O/l -> ctx ----
#pragma unroll
    for (int qg = 0; qg < 2; ++qg) {
        float lt = l_s[qg];
        lt += __shfl_xor(lt, 16);
        lt += __shfl_xor(lt, 32);
        float inv = 1.f / lt;
        size_t rowbase =
            ((size_t)(b * S_ + q0 + w * 32 + qg * 16 + c)) * 1024 + rh * 64;
#pragma unroll
        for (int t = 0; t < 4; ++t) {
            union { half4 v; fp16x2 h2[2]; } e;
            e.h2[0] = __builtin_amdgcn_cvt_pkrtz(o_acc[qg][t][0] * inv,
                                                 o_acc[qg][t][1] * inv);
            e.h2[1] = __builtin_amdgcn_cvt_pkrtz(o_acc[qg][t][2] * inv,
                                                 o_acc[qg][t][3] * inv);
            *(half4*)(ctx + rowbase + 16 * t + 4 * g) = e.v;
        }
    }
}

// --------------------- LayerNorm in place on y[4096][1024] -----------------
__global__ __launch_bounds__(256) void ln_kernel(
    float* __restrict__ y, const float* __restrict__ g, const float* __restrict__ bb)
{
    int row = blockIdx.x, tid = threadIdx.x;
    float* p = y + (size_t)row * 1024;
    float4 v = ((const float4*)p)[tid];
    float sum = v.x + v.y + v.z + v.w;
    float sq  = v.x*v.x + v.y*v.y + v.z*v.z + v.w*v.w;
#pragma unroll
    for (int off = 32; off > 0; off >>= 1) {
        sum += __shfl_xor(sum, off);
        sq  += __shfl_xor(sq,  off);
    }
    __shared__ float rs[4], rq[4];
    int w = tid >> 6;
    if ((tid & 63) == 0) { rs[w] = sum; rq[w] = sq; }
    __syncthreads();
    sum = rs[0] + rs[1] + rs[2] + rs[3];
    sq  = rq[0] + rq[1] + rq[2] + rq[3];
    float mean = sum * (1.f / 1024.f);
    float var  = sq * (1.f / 1024.f) - mean * mean;
    float inv  = rsqrtf(var + 1e-5f);
    float4 gv = ((const float4*)g)[tid];
    float4 bv = ((const float4*)bb)[tid];
    v.x = (v.x - mean) * inv * gv.x + bv.x;
    v.y = (v.y - mean) * inv * gv.y + bv.y;
    v.z = (v.z - mean) * inv * gv.z + bv.z;
    v.w = (v.w - mean) * inv * gv.w + bv.w;
    ((float4*)p)[tid] = v;
}

// ---------------------------------------------------------------------------
extern "C" void kernel_launch(void* const* d_in, const int* in_sizes, int n_in,
                              void* d_out, int out_size, void* d_ws, size_t ws_size,
                              hipStream_t stream)
{
    const float* x     = (const float*)d_in[0];
    const float* pos   = (const float*)d_in[1];
    const float* W_qkv = (const float*)d_in[2];
    const float* b_qkv = (const float*)d_in[3];
    const float* W_out = (const float*)d_in[4];
    const float* b_out = (const float*)d_in[5];
    const float* ln_g  = (const float*)d_in[6];
    const float* ln_b  = (const float*)d_in[7];
    float* out = (float*)d_out;

    char* ws = (char*)d_ws;
    _Float16* x_h    = (_Float16*)(ws);                       //  8 MB
    _Float16* wqkv_t = (_Float16*)(ws + ((size_t)8  << 20));  //  6 MB
    _Float16* wout_t = (_Float16*)(ws + ((size_t)14 << 20));  //  2 MB
    float*    qkv    = (float*)   (ws + ((size_t)16 << 20));  // 48 MB
    _Float16* qt_h   = (_Float16*)(ws + ((size_t)64 << 20));  //  8 MB
    _Float16* kt_h   = (_Float16*)(ws + ((size_t)72 << 20));  //  8 MB
    _Float16* vt2_h  = (_Float16*)(ws + ((size_t)80 << 20));  //  8 MB
    _Float16* ctx_h  = (_Float16*)(ws + ((size_t)88 << 20));  //  8 MB

    cast_f16_kernel<<<4096, 256, 0, stream>>>(x, x_h, BS_ * H_);
    transpose_cast_f16<<<dim3(96, 32), 256, 0, stream>>>(W_qkv, wqkv_t, H_, NQKV);
    transpose_cast_f16<<<dim3(32, 32), 256, 0, stream>>>(W_out, wout_t, H_, H_);

    gemm_f16_mfma<<<dim3(NQKV / 128, BS_ / 128), 256, 0, stream>>>(
        x_h, wqkv_t, b_qkv, nullptr, qkv, BS_, NQKV, H_);

    rope_kernel<<<BS_ * R_ / 4, 256, 0, stream>>>(qkv, pos, qt_h, kt_h);
    vtrans_kernel<<<dim3(32, 32), 256, 0, stream>>>(qkv, vt2_h);

    attn_mfma_kernel<<<dim3(32, 16), 256, 0, stream>>>(qt_h, kt_h, vt2_h, ctx_h);

    gemm_f16_mfma<<<dim3(H_ / 128, BS_ / 128), 256, 0, stream>>>(
        ctx_h, wout_t, b_out, x, out, BS_, H_, H_);

    ln_kernel<<<BS_, 256, 0, stream>>>(out, ln_g, ln_b);
}